// Round 10
// baseline (321.973 us; speedup 1.0000x reference)
//
#include <hip/hip_runtime.h>

#define N_NODES 20000
#define N_EDGES 640000
#define OBS 64
#define HDIM 256
#define MSGD 128
#define ADIM 16
#define Q_OFF 0
#define HN_OFF (N_NODES * ADIM)   // 320000

typedef __bf16 bf16x8 __attribute__((ext_vector_type(8)));
typedef float  f32x4  __attribute__((ext_vector_type(4)));

__device__ __forceinline__ unsigned short f2bf(float f) {
    union { float f; unsigned int i; } v; v.f = f;
    unsigned int i = v.i;
    return (unsigned short)((i + 0x7fffu + ((i >> 16) & 1u)) >> 16);
}
__device__ __forceinline__ float bf2f(unsigned short u) {
    union { unsigned int i; float f; } v; v.i = ((unsigned int)u) << 16; return v.f;
}
__device__ __forceinline__ bf16x8 ld8(const unsigned short* p) {
    bf16x8 r;
    __builtin_memcpy(&r, __builtin_assume_aligned(p, 16), 16);
    return r;
}
__device__ __forceinline__ f32x4 mfma16(bf16x8 a, bf16x8 b, f32x4 c) {
    return __builtin_amdgcn_mfma_f32_16x16x32_bf16(a, b, c, 0, 0, 0);
}
__device__ __forceinline__ float sigmoidf_(float x) { return 1.0f / (1.0f + __expf(-x)); }
__device__ __forceinline__ float tanhf_(float x) { return 2.0f / (1.0f + __expf(-2.0f * x)) - 1.0f; }

// fragment-packed layout: element (row,k) of a K-major matrix, Kc=K/32:
__device__ __forceinline__ int packIdx(int row, int k, int Kc) {
    return ((row >> 4) * Kc + (k >> 5)) * 512 + (((k >> 3) & 3) * 16 + (row & 15)) * 8 + (k & 7);
}
__device__ __forceinline__ int packIdxEp(int tile, int rlow, int t, int lr, int Kc) {
    return (tile * Kc + (t >> 1)) * 512 + (((t & 1) * 2 + (lr >> 3)) * 16 + rlow) * 8 + (lr & 7);
}
// block-local LDS variant (tile folded out): chunk = t>>1
__device__ __forceinline__ int packIdxLoc(int rlow, int t, int lr) {
    return (t >> 1) * 512 + (((t & 1) * 2 + (lr >> 3)) * 16 + rlow) * 8 + (lr & 7);
}

// ---------------- ws layout (bytes) ----------------
#define WS_W0P    0u
#define WS_W1P    32768u
#define WS_WMP    163840u
#define WS_WGP    294912u
#define WS_WOP    1277952u
#define WS_FEATP  1286144u
#define WS_HBP    3846144u
#define WS_XP     24326144u
#define WS_MN     34566144u
#define WS_CP     39686144u
#define WS_HNP    44806144u
#define WS_DEG    55046144u   // 20000 int (80000 B)
#define WS_TICKET 55126144u   // 1 int ticket (zeroed with deg; 64B pad)
#define WS_OFF    55126208u
#define WS_CUR    55206208u
#define WS_BUCKET 55286208u   // 640000 int (end 57846208)

#define GATE_STRIDE 163840

// fused setup: histogram + ticket-gated inline scan + all packing.
// Ticket pattern (no waiting, deadlock-free): last block to finish its
// histogram share performs the prefix scan itself.
// R10 FIX: R9's inline scan did 160 SERIAL device-atomic round-trips per
// thread (`run += atomicAdd(deg)` chains) -- at ~0.6-0.7us per cross-die
// atomic RMW that was ~100us in ONE wave (measured: setup 120us, VALUBusy
// 1.0%, everything idle). Now: 20000 INDEPENDENT coalesced L2-coherent
// loads into a 40KB LDS ushort copy (deg max ~70 for this input), then all
// prefix arithmetic on LDS.
__global__ __launch_bounds__(256) void setup_kernel(
    const float* __restrict__ feat, const float* __restrict__ h,
    const float* __restrict__ w0, const float* __restrict__ w1, const float* __restrict__ wm,
    const float* __restrict__ wih, const float* __restrict__ whh, const float* __restrict__ wo,
    const int* __restrict__ dst,
    unsigned short* __restrict__ featp, unsigned short* __restrict__ hbp,
    unsigned short* __restrict__ w0p, unsigned short* __restrict__ w1p,
    unsigned short* __restrict__ wmp, unsigned short* __restrict__ wgp,
    unsigned short* __restrict__ wop,
    int* __restrict__ deg, int* __restrict__ off, int* __restrict__ cur,
    int* __restrict__ ticket)
{
    const int tid = blockIdx.x * 256 + threadIdx.x;
    const int np = gridDim.x * 256;
    const int nb = gridDim.x;

    // ---- histogram (deg pre-zeroed by host memset) ----
    for (int i = tid; i < N_EDGES; i += np) atomicAdd(&deg[dst[i]], 1);

    // ---- ticket: last block to finish histogram does the scan inline ----
    __shared__ int isLast;
    __syncthreads();
    if (threadIdx.x == 0) {
        __threadfence();
        int old = atomicAdd(ticket, 1);
        isLast = (old == nb - 1) ? 1 : 0;
    }
    __syncthreads();
    if (isLast) {
        __shared__ unsigned short sdeg[N_NODES];   // 40 KB
        __shared__ int part[256];
        const int t = threadIdx.x;
        // parallel, independent, lane-coalesced coherent reads (no RMW chain)
        for (int i = t; i < N_NODES; i += 256)
            sdeg[i] = (unsigned short)__hip_atomic_load(&deg[i], __ATOMIC_RELAXED,
                                                        __HIP_MEMORY_SCOPE_AGENT);
        __syncthreads();
        const int base = t * 80;
        int s = 0;
        #pragma unroll 8
        for (int i = 0; i < 80; ++i) { int idx = base + i; if (idx < N_NODES) s += sdeg[idx]; }
        part[t] = s;
        __syncthreads();
        int acc = s;
        for (int d = 1; d < 256; d <<= 1) {
            int v = (t >= d) ? part[t - d] : 0;
            __syncthreads();
            acc += v; part[t] = acc;
            __syncthreads();
        }
        int run = acc - s;
        for (int i = 0; i < 80; ++i) {
            int idx = base + i;
            if (idx < N_NODES) { off[idx] = run; cur[idx] = run; run += sdeg[idx]; }
        }
    }

    // ---- activation packing (R6-vectorized bodies) ----
    for (int ch = tid; ch < N_NODES * OBS / 8; ch += np) {
        int row = ch >> 3, k = (ch & 7) * 8;
        const float4* p = (const float4*)(feat + row * OBS + k);
        float4 a = p[0], b = p[1];
        union { unsigned short u[8]; uint4 v; } r;
        r.u[0]=f2bf(a.x); r.u[1]=f2bf(a.y); r.u[2]=f2bf(a.z); r.u[3]=f2bf(a.w);
        r.u[4]=f2bf(b.x); r.u[5]=f2bf(b.y); r.u[6]=f2bf(b.z); r.u[7]=f2bf(b.w);
        *(uint4*)(featp + packIdx(row, k, 2)) = r.v;
    }
    for (int ch = tid; ch < N_NODES * HDIM / 8; ch += np) {
        int row = ch >> 5, k = (ch & 31) * 8;
        const float4* p = (const float4*)(h + row * HDIM + k);
        float4 a = p[0], b = p[1];
        union { unsigned short u[8]; uint4 v; } r;
        r.u[0]=f2bf(a.x); r.u[1]=f2bf(a.y); r.u[2]=f2bf(a.z); r.u[3]=f2bf(a.w);
        r.u[4]=f2bf(b.x); r.u[5]=f2bf(b.y); r.u[6]=f2bf(b.z); r.u[7]=f2bf(b.w);
        *(uint4*)(hbp + packIdx(row, k, 8)) = r.v;
    }
    // weight packs: 8 coalesced f32 loads -> one aligned uint4 store
    for (int it = tid; it < 256 * 8; it += np) {          // W0: 64x256
        int n = it & 255, kb = it >> 8;
        union { unsigned short u[8]; uint4 v; } r;
        #pragma unroll
        for (int j = 0; j < 8; ++j) r.u[j] = f2bf(w0[(kb * 8 + j) * 256 + n]);
        *(uint4*)(w0p + packIdx(n, kb * 8, 2)) = r.v;
    }
    for (int it = tid; it < 256 * 32; it += np) {         // W1: 256x256
        int n = it & 255, kb = it >> 8;
        union { unsigned short u[8]; uint4 v; } r;
        #pragma unroll
        for (int j = 0; j < 8; ++j) r.u[j] = f2bf(w1[(kb * 8 + j) * 256 + n]);
        *(uint4*)(w1p + packIdx(n, kb * 8, 8)) = r.v;
    }
    for (int it = tid; it < 128 * 64; it += np) {         // Wm: 512x128
        int n = it & 127, kb = it >> 7;
        union { unsigned short u[8]; uint4 v; } r;
        #pragma unroll
        for (int j = 0; j < 8; ++j) r.u[j] = f2bf(wm[(kb * 8 + j) * 128 + n]);
        *(uint4*)(wmp + packIdx(n, kb * 8, 16)) = r.v;
    }
    for (int it = tid; it < 768 * 48; it += np) {         // Wih: 384x768
        int c3 = it % 768, kb = it / 768;
        union { unsigned short u[8]; uint4 v; } r;
        #pragma unroll
        for (int j = 0; j < 8; ++j) r.u[j] = f2bf(wih[(kb * 8 + j) * 768 + c3]);
        *(uint4*)(wgp + (c3 >> 8) * GATE_STRIDE + packIdx(c3 & 255, kb * 8, 20)) = r.v;
    }
    for (int it = tid; it < 768 * 32; it += np) {         // Whh: 256x768 (k offset 384)
        int c3 = it % 768, kb = it / 768;
        union { unsigned short u[8]; uint4 v; } r;
        #pragma unroll
        for (int j = 0; j < 8; ++j) r.u[j] = f2bf(whh[(kb * 8 + j) * 768 + c3]);
        *(uint4*)(wgp + (c3 >> 8) * GATE_STRIDE + packIdx(c3 & 255, 384 + kb * 8, 20)) = r.v;
    }
    for (int it = tid; it < 16 * 32; it += np) {          // Wo: 256x16
        int n = it & 15, kb = it >> 4;
        union { unsigned short u[8]; uint4 v; } r;
        #pragma unroll
        for (int j = 0; j < 8; ++j) r.u[j] = f2bf(wo[(kb * 8 + j) * 16 + n]);
        *(uint4*)(wop + packIdx(n, kb * 8, 8)) = r.v;
    }
}

// fused encoder + edge scatter (independent work, one dispatch):
// blocks 0..625: enc0 -> enc1 -> msg (R6 body, 32-row slab).
// blocks 626..3125: edge scatter (bucket[pos]=src) -- its latency-bound
// atomics hide under the enc blocks' MFMA work instead of serializing.
__global__ __launch_bounds__(256) void enc_scatter_kernel(
    const unsigned short* __restrict__ featp, const unsigned short* __restrict__ hbp,
    const unsigned short* __restrict__ w0p, const float* __restrict__ b0,
    const unsigned short* __restrict__ w1p, const float* __restrict__ b1,
    const unsigned short* __restrict__ wmp, const float* __restrict__ mb,
    unsigned short* __restrict__ Xp, unsigned short* __restrict__ Mn,
    const int* __restrict__ src, const int* __restrict__ dst,
    int* __restrict__ cur, int* __restrict__ bucket)
{
    __shared__ __align__(16) unsigned short x0l[2][8][512];  // 16 KB
    __shared__ __align__(16) unsigned short x1l[2][8][512];  // 16 KB

    if (blockIdx.x >= 626) {
        // ---- scatter part ----
        int i = (blockIdx.x - 626) * 256 + threadIdx.x;
        if (i < N_EDGES) {
            int d = dst[i];
            int pos = atomicAdd(&cur[d], 1);
            if (pos < N_EDGES) bucket[pos] = src[i];   // replay-safe bound check
        }
        return;
    }

    // ---- enc part (R6 body, unchanged) ----
    const int wave = threadIdx.x >> 6;
    const int lane = threadIdx.x & 63, lr = lane & 15, lq = lane >> 4;
    const int m32 = blockIdx.x;          // 0..625
    int tG[2]; bool val[2];
    #pragma unroll
    for (int mf = 0; mf < 2; ++mf) { int tl = m32 * 2 + mf; val[mf] = tl < 1250; tG[mf] = val[mf] ? tl : 1249; }

    // ---- Stage A: X0 = relu(feat @ W0 + b0) -> LDS ----
    for (int i = 0; i < 4; ++i) {
        const int t = wave * 4 + i;
        f32x4 acc[2] = {{0,0,0,0},{0,0,0,0}};
        for (int c = 0; c < 2; ++c) {
            bf16x8 b = ld8(w0p + (t * 2 + c) * 512 + lane * 8);
            #pragma unroll
            for (int mf = 0; mf < 2; ++mf) {
                bf16x8 a = ld8(featp + (tG[mf] * 2 + c) * 512 + lane * 8);
                acc[mf] = mfma16(a, b, acc[mf]);
            }
        }
        float bias = b0[t * 16 + lr];
        #pragma unroll
        for (int mf = 0; mf < 2; ++mf)
            #pragma unroll
            for (int r = 0; r < 4; ++r)
                (&x0l[mf][0][0])[packIdxLoc(lq * 4 + r, t, lr)] = f2bf(fmaxf(acc[mf][r] + bias, 0.f));
    }
    __syncthreads();
    // ---- Stage B: X = relu(X0 @ W1 + b1) -> LDS + packed global ----
    for (int i = 0; i < 4; ++i) {
        const int t = wave * 4 + i;
        f32x4 acc[2] = {{0,0,0,0},{0,0,0,0}};
        for (int c = 0; c < 8; ++c) {
            bf16x8 b = ld8(w1p + (t * 8 + c) * 512 + lane * 8);
            #pragma unroll
            for (int mf = 0; mf < 2; ++mf) {
                bf16x8 a = ld8(&x0l[mf][c][lane * 8]);
                acc[mf] = mfma16(a, b, acc[mf]);
            }
        }
        float bias = b1[t * 16 + lr];
        #pragma unroll
        for (int mf = 0; mf < 2; ++mf)
            #pragma unroll
            for (int r = 0; r < 4; ++r) {
                unsigned short xb = f2bf(fmaxf(acc[mf][r] + bias, 0.f));
                (&x1l[mf][0][0])[packIdxLoc(lq * 4 + r, t, lr)] = xb;
                if (val[mf]) Xp[packIdxEp(tG[mf], lq * 4 + r, t, lr, 8)] = xb;
            }
    }
    __syncthreads();
    // ---- Stage C: Mnode = X @ Wx + h @ Wh + mb -> row-major global ----
    for (int i = 0; i < 2; ++i) {
        const int t = wave * 2 + i;          // 0..7
        const int col = t * 16 + lr;
        f32x4 acc[2] = {{0,0,0,0},{0,0,0,0}};
        for (int c = 0; c < 8; ++c) {        // X part, A from LDS
            bf16x8 b = ld8(wmp + (t * 16 + c) * 512 + lane * 8);
            #pragma unroll
            for (int mf = 0; mf < 2; ++mf) {
                bf16x8 a = ld8(&x1l[mf][c][lane * 8]);
                acc[mf] = mfma16(a, b, acc[mf]);
            }
        }
        for (int c = 0; c < 8; ++c) {        // h part
            bf16x8 b = ld8(wmp + (t * 16 + 8 + c) * 512 + lane * 8);
            #pragma unroll
            for (int mf = 0; mf < 2; ++mf) {
                bf16x8 a = ld8(hbp + (tG[mf] * 8 + c) * 512 + lane * 8);
                acc[mf] = mfma16(a, b, acc[mf]);
            }
        }
        float bias = mb[col];
        #pragma unroll
        for (int mf = 0; mf < 2; ++mf) if (val[mf])
            #pragma unroll
            for (int r = 0; r < 4; ++r) {
                int row = m32 * 32 + mf * 16 + lq * 4 + r;
                Mn[row * MSGD + col] = f2bf(acc[mf][r] + bias);
            }
    }
}

// one wave per node: gather Mn rows, mean, write packed C row.
// 2 rows per gather instruction: lanes 0-31 even edges, 32-63 odd edges,
// uint2/lane => 512 B/instr. Cross-half combine via shfl_xor(32).
__global__ __launch_bounds__(256) void aggregate_kernel(
    const int* __restrict__ off, const int* __restrict__ deg,
    const int* __restrict__ bucket, const unsigned short* __restrict__ Mn,
    unsigned short* __restrict__ Cp)
{
    const int wave = threadIdx.x >> 6;
    const int lane = threadIdx.x & 63;
    const int half = lane >> 5;          // 0: even edges, 1: odd edges
    const int l32  = lane & 31;          // cols 4*l32 .. 4*l32+3
    const int node = blockIdx.x * 4 + wave;
    if (node >= N_NODES) return;
    const int o = off[node], dg = deg[node];
    float s0 = 0.f, s1 = 0.f, s2 = 0.f, s3 = 0.f;
    const uint2* mn2 = (const uint2*)Mn;   // Mn row = 32 uint2
    int j = 0;
    for (; j + 8 <= dg; j += 8) {
        int ix[8];
        #pragma unroll
        for (int u = 0; u < 8; ++u) ix[u] = bucket[o + j + u];
        uint2 pk[4];
        #pragma unroll
        for (int p = 0; p < 4; ++p) pk[p] = mn2[ix[p * 2 + half] * 32 + l32];
        #pragma unroll
        for (int p = 0; p < 4; ++p) {
            s0 += bf2f((unsigned short)(pk[p].x & 0xffffu));
            s1 += bf2f((unsigned short)(pk[p].x >> 16));
            s2 += bf2f((unsigned short)(pk[p].y & 0xffffu));
            s3 += bf2f((unsigned short)(pk[p].y >> 16));
        }
    }
    for (; j + 2 <= dg; j += 2) {
        int i0 = bucket[o + j + half];
        uint2 pk = mn2[i0 * 32 + l32];
        s0 += bf2f((unsigned short)(pk.x & 0xffffu));
        s1 += bf2f((unsigned short)(pk.x >> 16));
        s2 += bf2f((unsigned short)(pk.y & 0xffffu));
        s3 += bf2f((unsigned short)(pk.y >> 16));
    }
    if (j < dg) {                         // odd remainder: only half 0 counts it
        int i0 = bucket[o + j];
        uint2 pk = mn2[i0 * 32 + l32];
        if (half == 0) {
            s0 += bf2f((unsigned short)(pk.x & 0xffffu));
            s1 += bf2f((unsigned short)(pk.x >> 16));
            s2 += bf2f((unsigned short)(pk.y & 0xffffu));
            s3 += bf2f((unsigned short)(pk.y >> 16));
        }
    }
    s0 += __shfl_xor(s0, 32);
    s1 += __shfl_xor(s1, 32);
    s2 += __shfl_xor(s2, 32);
    s3 += __shfl_xor(s3, 32);
    if (half == 0) {
        float invc = 1.0f / fmaxf((float)dg, 1.0f);
        uint2 outpk;
        outpk.x = ((unsigned int)f2bf(s1 * invc) << 16) | (unsigned int)f2bf(s0 * invc);
        outpk.y = ((unsigned int)f2bf(s3 * invc) << 16) | (unsigned int)f2bf(s2 * invc);
        *(uint2*)(Cp + packIdx(node, 4 * l32, 4)) = outpk;
    }
}

// ---------------- gru: XCD-partitioned persistent blocks + asm pipeline ----------------
// (unchanged from R5/R6 -- validated: gru < 41 us)
__global__ __launch_bounds__(512, 4) void gru_kernel(
    const unsigned short* __restrict__ Xp, const unsigned short* __restrict__ Cp,
    const unsigned short* __restrict__ hbp, const float* __restrict__ h,
    const unsigned short* __restrict__ wgp,
    const float* __restrict__ bih, const float* __restrict__ bhh,
    unsigned short* __restrict__ Hnp, float* __restrict__ out)
{
#define GL4(dst, ptr) asm volatile("global_load_dwordx4 %0, %1, off" : "=v"(dst) : "v"(ptr))
#define GLDW(dst, ptr, IMM) asm volatile("global_load_dword %0, %1, off offset:" #IMM : "=v"(dst) : "v"(ptr))
#define WAITV(N) do { asm volatile("s_waitcnt vmcnt(" #N ")" ::: "memory"); \
                      __builtin_amdgcn_sched_barrier(0); } while (0)
#define ISSUE2(cn) do { \
    const unsigned short *p0_, *p1_; \
    if ((cn) < 8)       { p0_ = bX + (cn) * 512;        p1_ = bX + 4096 + (cn) * 512; } \
    else if ((cn) < 12) { p0_ = bC + ((cn) - 8) * 512;  p1_ = bC + 2048 + ((cn) - 8) * 512; } \
    else                { p0_ = bH + ((cn) - 12) * 512; p1_ = bH + 4096 + ((cn) - 12) * 512; } \
    GL4(ring[(cn) & 3][0], p0_); GL4(ring[(cn) & 3][1], p1_); } while (0)
#define ISSUE1(cn) do { \
    const unsigned short *p_; \
    if ((cn) < 8)       p_ = bX + (cn) * 512; \
    else if ((cn) < 12) p_ = bC + ((cn) - 8) * 512; \
    else                p_ = bH + ((cn) - 12) * 512; \
    GL4(ring[(cn) & 3][0], p_); } while (0)
#define STEP(c, W) do { \
    bf16x8 br_ = ld8(&wlds[0][(c) * 512 + l8]); \
    bf16x8 bz_ = ld8(&wlds[1][(c) * 512 + l8]); \
    bf16x8 bn_ = ld8(&wlds[2][(c) * 512 + l8]); \
    WAITV(W); \
    bf16x8 a0_, a1_; \
    __builtin_memcpy(&a0_, &ring[(c) & 3][0], 16); \
    __builtin_memcpy(&a1_, &ring[(c) & 3][1], 16); \
    ar[0] = mfma16(a0_, br_, ar[0]);  ar[1] = mfma16(a1_, br_, ar[1]); \
    az[0] = mfma16(a0_, bz_, az[0]);  az[1] = mfma16(a1_, bz_, az[1]); \
    if ((c) < 12) { ani[0] = mfma16(a0_, bn_, ani[0]); ani[1] = mfma16(a1_, bn_, ani[1]); } \
    else          { anh[0] = mfma16(a0_, bn_, anh[0]); anh[1] = mfma16(a1_, bn_, anh[1]); } \
    if ((c) + 4 < 20) ISSUE2((c) + 4); \
    if ((c) == 15) { \
        GLDW(hov[0][0], hb0, 0); GLDW(hov[0][1], hb0, 1024); \
        GLDW(hov[0][2], hb0, 2048); GLDW(hov[0][3], hb0, 3072); \
        GLDW(hov[1][0], hb1, 0); GLDW(hov[1][1], hb1, 1024); \
        GLDW(hov[1][2], hb1, 2048); GLDW(hov[1][3], hb1, 3072); \
    } } while (0)
#define HSTEP(c, W) do { \
    bf16x8 br_ = ld8(&wlds[0][(c) * 512 + l8]); \
    bf16x8 bz_ = ld8(&wlds[1][(c) * 512 + l8]); \
    bf16x8 bn_ = ld8(&wlds[2][(c) * 512 + l8]); \
    WAITV(W); \
    bf16x8 a0_; \
    __builtin_memcpy(&a0_, &ring[(c) & 3][0], 16); \
    ar[0] = mfma16(a0_, br_, ar[0]); \
    az[0] = mfma16(a0_, bz_, az[0]); \
    if ((c) < 12) ani[0] = mfma16(a0_, bn_, ani[0]); \
    else          anh[0] = mfma16(a0_, bn_, anh[0]); \
    if ((c) + 4 < 20) ISSUE1((c) + 4); \
    if ((c) == 15) { \
        GLDW(hov[0][0], hb0, 0); GLDW(hov[0][1], hb0, 1024); \
        GLDW(hov[0][2], hb0, 2048); GLDW(hov[0][3], hb0, 3072); \
    } } while (0)
#define SETBASES32(m) do { \
    bX = Xp  + (m) * 8192 + l8; \
    bC = Cp  + (m) * 4096 + l8; \
    bH = hbp + (m) * 8192 + l8; \
    hb0 = h + ((m) * 32 + lq * 4) * HDIM + col; \
    hb1 = hb0 + 16 * HDIM; } while (0)
#define EPILOG32(m) do { \
    _Pragma("unroll") \
    for (int mf = 0; mf < 2; ++mf) \
        _Pragma("unroll") \
        for (int r = 0; r < 4; ++r) { \
            int row = (m) * 32 + mf * 16 + lq * 4 + r; \
            float rg = sigmoidf_(ar[mf][r] + bir); \
            float zg = sigmoidf_(az[mf][r] + biz); \
            float ng = tanhf_(ani[mf][r] + bin + rg * (anh[mf][r] + bhn)); \
            float hn = (1.0f - zg) * ng + zg * hov[mf][r]; \
            out[HN_OFF + row * HDIM + col] = hn; \
            Hnp[packIdxEp((m) * 2 + mf, lq * 4 + r, t, lr, 8)] = f2bf(hn); \
        } } while (0)
#define ACCINIT() do { \
    _Pragma("unroll") \
    for (int mf = 0; mf < 2; ++mf) { \
        ar[mf]  = (f32x4){0,0,0,0}; az[mf]  = (f32x4){0,0,0,0}; \
        ani[mf] = (f32x4){0,0,0,0}; anh[mf] = (f32x4){0,0,0,0}; } } while (0)

    __shared__ __align__(16) unsigned short wlds[3][10240];  // 60 KB

    const int b = blockIdx.x;            // 0..511
    const int x = b & 7;                 // XCD-partition label (%8 round-robin)
    const int i = b >> 3;                // 0..63
    const int t = i & 15;                // col tile (block-uniform)
    const int wi = i >> 4;               // 0..3
    const int tid = threadIdx.x;
    const int wv = tid >> 6;             // 0..7
    const int lane = tid & 63, lr = lane & 15, lq = lane >> 4;
    const int l8 = lane * 8;
    const int widx = wi * 8 + wv;        // 0..31 within (x,t)
    const int start = x * 78 + (x ? 1 : 0);
    const int cnt = 78 + (x == 0 ? 1 : 0);
    const int col = t * 16 + lr;

    const int m32a = start + widx;            // full tile 1
    const int m32b = start + 32 + widx;       // full tile 2
    const int halves = 2 * (cnt - 64);        // 28 or 30
    const bool has_tail = widx < halves;
    const int m32t = start + 64 + (widx >> 1);
    const int hm = widx & 1;                  // which 16-row half

    const unsigned short *bX, *bC, *bH;
    const float *hb0, *hb1;
    uint4 ring[4][2];
    f32x4 ar[2], az[2], ani[2], anh[2];
    float hov[2][4];

    // tile-A prologue BEFORE staging: staging loop + barrier (compiler emits
    // vmcnt(0) drain before s_barrier) hides + retires chunks 0..3.
    SETBASES32(m32a);
    ISSUE2(0); ISSUE2(1); ISSUE2(2); ISSUE2(3);

    // stage 3-gate weights for col-tile t: 61440 B = 3840 uint4 over 512 threads
    for (int s = tid; s < 3840; s += 512) {
        int g = s / 1280, rem = s - g * 1280;
        const uint4* sp = (const uint4*)(wgp + g * GATE_STRIDE + t * 10240) + rem;
        *((uint4*)(&wlds[g][0]) + rem) = *sp;
    }
    const float bir = bih[col] + bhh[col];
    const float biz = bih[256 + col] + bhh[256 + col];
    const float bin = bih[512 + col];
    const float bhn = bhh[512 + col];
    __syncthreads();

    // ---- tile A (m32a) ----
    ACCINIT();
    STEP(0, 22);  STEP(1, 22);  STEP(2, 22);  STEP(3, 22);
    STEP(4, 6);   STEP(5, 6);   STEP(6, 6);   STEP(7, 6);
    STEP(8, 6);   STEP(9, 6);   STEP(10, 6);  STEP(11, 6);
    STEP(12, 6);  STEP(13, 6);  STEP(14, 6);  STEP(15, 6);
    STEP(16, 14); STEP(17, 12); STEP(18, 10); STEP(19, 8);
    SETBASES32(m32b);
    ISSUE2(0); ISSUE2(1); ISSUE2(2); ISSUE2(3);
    WAITV(8);                      // retire hoA (8 prologue loads younger)
    EPILOG32(m32a);                // 16 stores

    // ---- tile B (m32b) ----
    ACCINIT();
    STEP(0, 22);  STEP(1, 22);  STEP(2, 22);  STEP(3, 22);
    STEP(4, 6);   STEP(5, 6);   STEP(6, 6);   STEP(7, 6);
    STEP(8, 6);   STEP(9, 6);   STEP(10, 6);  STEP(11, 6);
    STEP(12, 6);  STEP(13, 6);  STEP(14, 6);  STEP(15, 6);
    STEP(16, 14); STEP(17, 12); STEP(18, 10); STEP(19, 8);

    if (has_tail) {
        // half-tile bases: 16-row tile index = m32t*2 + hm
        bX = Xp  + (m32t * 2 + hm) * 4096 + l8;
        bC = Cp  + (m32t * 2 + hm) * 2048 + l8;
        bH = hbp + (m32t * 2 + hm) * 4096 + l8;
        hb0 = h + (m32t * 32 + hm * 16 + lq * 4) * HDIM + col;
        ISSUE1(0); ISSUE1(1); ISSUE1(2); ISSUE1(3);
        WAITV(4);                  // retire hoB (4 tail loads younger)
        EPILOG32(m32b);            // 16 stores
        // ---- half tile (m32t, half hm) ----
        ACCINIT();
        HSTEP(0, 19);  HSTEP(1, 19);  HSTEP(2, 19);  HSTEP(3, 19);
        HSTEP(4, 3);   HSTEP(5, 3);   HSTEP(6, 3);   HSTEP(7, 3);
        HSTEP(8, 3);   HSTEP(9, 3);   HSTEP(10, 3);  HSTEP(11, 3);
        HSTEP(12, 3);  HSTEP(13, 3);  HSTEP(14, 3);  HSTEP(15, 3);
        HSTEP(16, 7);  HSTEP(17, 6);  HSTEP(18, 5);  HSTEP(19, 4);
        WAITV(0);
        #pragma unroll
        for (int r = 0; r < 4; ++r) {
            int row = m32t * 32 + hm * 16 + lq * 4 + r;
            float rg = sigmoidf_(ar[0][r] + bir);
            float zg = sigmoidf_(az[0][r] + biz);
            float ng = tanhf_(ani[0][r] + bin + rg * (anh[0][r] + bhn));
            float hn = (1.0f - zg) * ng + zg * hov[0][r];
            out[HN_OFF + row * HDIM + col] = hn;
            Hnp[packIdxEp(m32t * 2 + hm, lq * 4 + r, t, lr, 8)] = f2bf(hn);
        }
    } else {
        WAITV(0);
        EPILOG32(m32b);
    }
#undef GL4
#undef GLDW
#undef WAITV
#undef ISSUE2
#undef ISSUE1
#undef STEP
#undef HSTEP
#undef SETBASES32
#undef EPILOG32
#undef ACCINIT
}

// q = h_new @ out_W + out_b. one wave per 16-row tile.
__global__ __launch_bounds__(256) void q_kernel(
    const unsigned short* __restrict__ Hnp, const unsigned short* __restrict__ wop,
    const float* __restrict__ ob, float* __restrict__ out)
{
    int w = blockIdx.x * 4 + (threadIdx.x >> 6);
    if (w >= 1250) w = 1249;
    const int lane = threadIdx.x & 63, lr = lane & 15, lq = lane >> 4;
    f32x4 acc = {0.f, 0.f, 0.f, 0.f};
    for (int c = 0; c < 8; ++c) {
        bf16x8 a = ld8(Hnp + (w * 8 + c) * 512 + lane * 8);
        bf16x8 b = ld8(wop + c * 512 + lane * 8);
        acc = mfma16(a, b, acc);
    }
    float bias = ob[lr];
    #pragma unroll
    for (int r = 0; r < 4; ++r)
        out[Q_OFF + (w * 16 + lq * 4 + r) * ADIM + lr] = acc[r] + bias;
}

extern "C" void kernel_launch(void* const* d_in, const int* in_sizes, int n_in,
                              void* d_out, int out_size, void* d_ws, size_t ws_size,
                              hipStream_t stream) {
    const float* feat = (const float*)d_in[0];
    const float* h    = (const float*)d_in[1];
    const int* src    = (const int*)d_in[2];
    const int* dst    = (const int*)d_in[3];
    const float* w0   = (const float*)d_in[4];
    const float* b0   = (const float*)d_in[5];
    const float* w1   = (const float*)d_in[6];
    const float* b1   = (const float*)d_in[7];
    const float* wm   = (const float*)d_in[8];
    const float* mb   = (const float*)d_in[9];
    const float* wih  = (const float*)d_in[10];
    const float* whh  = (const float*)d_in[11];
    const float* bih  = (const float*)d_in[12];
    const float* bhh  = (const float*)d_in[13];
    const float* wo   = (const float*)d_in[14];
    const float* ob   = (const float*)d_in[15];

    char* ws = (char*)d_ws;
    unsigned short* w0p   = (unsigned short*)(ws + WS_W0P);
    unsigned short* w1p   = (unsigned short*)(ws + WS_W1P);
    unsigned short* wmp   = (unsigned short*)(ws + WS_WMP);
    unsigned short* wgp   = (unsigned short*)(ws + WS_WGP);
    unsigned short* wop   = (unsigned short*)(ws + WS_WOP);
    unsigned short* featp = (unsigned short*)(ws + WS_FEATP);
    unsigned short* hbp   = (unsigned short*)(ws + WS_HBP);
    unsigned short* Xp    = (unsigned short*)(ws + WS_XP);
    unsigned short* Mn    = (unsigned short*)(ws + WS_MN);
    unsigned short* Cp    = (unsigned short*)(ws + WS_CP);
    unsigned short* Hnp   = (unsigned short*)(ws + WS_HNP);
    int* deg              = (int*)(ws + WS_DEG);
    int* ticket           = (int*)(ws + WS_TICKET);
    int* off              = (int*)(ws + WS_OFF);
    int* cur              = (int*)(ws + WS_CUR);
    int* bucket           = (int*)(ws + WS_BUCKET);
    float* out            = (float*)d_out;

    // zero deg (80000 B) + ticket (64 B pad) in one memset
    hipMemsetAsync(deg, 0, 80064, stream);
    hipLaunchKernelGGL(setup_kernel, dim3(2048), dim3(256), 0, stream,
                       feat, h, w0, w1, wm, wih, whh, wo, dst,
                       featp, hbp, w0p, w1p, wmp, wgp, wop,
                       deg, off, cur, ticket);
    hipLaunchKernelGGL(enc_scatter_kernel, dim3(626 + (N_EDGES + 255) / 256), dim3(256), 0, stream,
                       featp, hbp, w0p, b0, w1p, b1, wmp, mb, Xp, Mn,
                       src, dst, cur, bucket);
    hipLaunchKernelGGL(aggregate_kernel, dim3((N_NODES + 3) / 4), dim3(256), 0, stream,
                       off, deg, bucket, Mn, Cp);
    hipLaunchKernelGGL(gru_kernel, dim3(512), dim3(512), 0, stream,
                       Xp, Cp, hbp, h, wgp, bih, bhh, Hnp, out);
    hipLaunchKernelGGL(q_kernel, dim3(313), dim3(256), 0, stream, Hnp, wop, ob, out);
}

// Round 11
// 260.791 us; speedup vs baseline: 1.2346x; 1.2346x over previous
//
#include <hip/hip_runtime.h>

#define N_NODES 20000
#define N_EDGES 640000
#define OBS 64
#define HDIM 256
#define MSGD 128
#define ADIM 16
#define Q_OFF 0
#define HN_OFF (N_NODES * ADIM)   // 320000

typedef __bf16 bf16x8 __attribute__((ext_vector_type(8)));
typedef float  f32x4  __attribute__((ext_vector_type(4)));

__device__ __forceinline__ unsigned short f2bf(float f) {
    union { float f; unsigned int i; } v; v.f = f;
    unsigned int i = v.i;
    return (unsigned short)((i + 0x7fffu + ((i >> 16) & 1u)) >> 16);
}
__device__ __forceinline__ float bf2f(unsigned short u) {
    union { unsigned int i; float f; } v; v.i = ((unsigned int)u) << 16; return v.f;
}
__device__ __forceinline__ bf16x8 ld8(const unsigned short* p) {
    bf16x8 r;
    __builtin_memcpy(&r, __builtin_assume_aligned(p, 16), 16);
    return r;
}
__device__ __forceinline__ f32x4 mfma16(bf16x8 a, bf16x8 b, f32x4 c) {
    return __builtin_amdgcn_mfma_f32_16x16x32_bf16(a, b, c, 0, 0, 0);
}
__device__ __forceinline__ float sigmoidf_(float x) { return 1.0f / (1.0f + __expf(-x)); }
__device__ __forceinline__ float tanhf_(float x) { return 2.0f / (1.0f + __expf(-2.0f * x)) - 1.0f; }

// fragment-packed layout: element (row,k) of a K-major matrix, Kc=K/32:
__device__ __forceinline__ int packIdx(int row, int k, int Kc) {
    return ((row >> 4) * Kc + (k >> 5)) * 512 + (((k >> 3) & 3) * 16 + (row & 15)) * 8 + (k & 7);
}
__device__ __forceinline__ int packIdxEp(int tile, int rlow, int t, int lr, int Kc) {
    return (tile * Kc + (t >> 1)) * 512 + (((t & 1) * 2 + (lr >> 3)) * 16 + rlow) * 8 + (lr & 7);
}
// block-local LDS variant (tile folded out): chunk = t>>1
__device__ __forceinline__ int packIdxLoc(int rlow, int t, int lr) {
    return (t >> 1) * 512 + (((t & 1) * 2 + (lr >> 3)) * 16 + rlow) * 8 + (lr & 7);
}

// ---------------- ws layout (bytes) ----------------
#define WS_W0P    0u
#define WS_W1P    32768u
#define WS_WMP    163840u
#define WS_WGP    294912u
#define WS_WOP    1277952u
#define WS_FEATP  1286144u
#define WS_HBP    3846144u
#define WS_XP     24326144u
#define WS_MN     34566144u
#define WS_CP     39686144u
#define WS_HNP    44806144u
#define WS_DEG    55046144u   // 20000 int (80000 B)
#define WS_OFF    55126208u
#define WS_CUR    55206208u
#define WS_BUCKET 55286208u   // 640000 int (end 57846208)

#define GATE_STRIDE 163840

// fused setup: histogram + all packing. NO ticket/fence/in-kernel scan:
// R9/R10 PMC showed the ticket + __threadfence structure cost ~80-105us
// (same FETCH/WRITE as R6, VALUBusy 3.6% -> 0.9%, time 41 -> 120/148us) --
// device-scope fences emit L2 writebacks; 2048 blocks of them is a cache
// flush storm. Kernel-boundary visibility (separate scan dispatch) is free.
__global__ __launch_bounds__(256) void setup_kernel(
    const float* __restrict__ feat, const float* __restrict__ h,
    const float* __restrict__ w0, const float* __restrict__ w1, const float* __restrict__ wm,
    const float* __restrict__ wih, const float* __restrict__ whh, const float* __restrict__ wo,
    const int* __restrict__ dst,
    unsigned short* __restrict__ featp, unsigned short* __restrict__ hbp,
    unsigned short* __restrict__ w0p, unsigned short* __restrict__ w1p,
    unsigned short* __restrict__ wmp, unsigned short* __restrict__ wgp,
    unsigned short* __restrict__ wop, int* __restrict__ deg)
{
    const int tid = blockIdx.x * 256 + threadIdx.x;
    const int np = gridDim.x * 256;

    // ---- histogram (deg pre-zeroed by host memset) ----
    for (int i = tid; i < N_EDGES; i += np) atomicAdd(&deg[dst[i]], 1);

    // ---- activation packing (R6-vectorized bodies) ----
    for (int ch = tid; ch < N_NODES * OBS / 8; ch += np) {
        int row = ch >> 3, k = (ch & 7) * 8;
        const float4* p = (const float4*)(feat + row * OBS + k);
        float4 a = p[0], b = p[1];
        union { unsigned short u[8]; uint4 v; } r;
        r.u[0]=f2bf(a.x); r.u[1]=f2bf(a.y); r.u[2]=f2bf(a.z); r.u[3]=f2bf(a.w);
        r.u[4]=f2bf(b.x); r.u[5]=f2bf(b.y); r.u[6]=f2bf(b.z); r.u[7]=f2bf(b.w);
        *(uint4*)(featp + packIdx(row, k, 2)) = r.v;
    }
    for (int ch = tid; ch < N_NODES * HDIM / 8; ch += np) {
        int row = ch >> 5, k = (ch & 31) * 8;
        const float4* p = (const float4*)(h + row * HDIM + k);
        float4 a = p[0], b = p[1];
        union { unsigned short u[8]; uint4 v; } r;
        r.u[0]=f2bf(a.x); r.u[1]=f2bf(a.y); r.u[2]=f2bf(a.z); r.u[3]=f2bf(a.w);
        r.u[4]=f2bf(b.x); r.u[5]=f2bf(b.y); r.u[6]=f2bf(b.z); r.u[7]=f2bf(b.w);
        *(uint4*)(hbp + packIdx(row, k, 8)) = r.v;
    }
    // weight packs: 8 coalesced f32 loads -> one aligned uint4 store
    for (int it = tid; it < 256 * 8; it += np) {          // W0: 64x256
        int n = it & 255, kb = it >> 8;
        union { unsigned short u[8]; uint4 v; } r;
        #pragma unroll
        for (int j = 0; j < 8; ++j) r.u[j] = f2bf(w0[(kb * 8 + j) * 256 + n]);
        *(uint4*)(w0p + packIdx(n, kb * 8, 2)) = r.v;
    }
    for (int it = tid; it < 256 * 32; it += np) {         // W1: 256x256
        int n = it & 255, kb = it >> 8;
        union { unsigned short u[8]; uint4 v; } r;
        #pragma unroll
        for (int j = 0; j < 8; ++j) r.u[j] = f2bf(w1[(kb * 8 + j) * 256 + n]);
        *(uint4*)(w1p + packIdx(n, kb * 8, 8)) = r.v;
    }
    for (int it = tid; it < 128 * 64; it += np) {         // Wm: 512x128
        int n = it & 127, kb = it >> 7;
        union { unsigned short u[8]; uint4 v; } r;
        #pragma unroll
        for (int j = 0; j < 8; ++j) r.u[j] = f2bf(wm[(kb * 8 + j) * 128 + n]);
        *(uint4*)(wmp + packIdx(n, kb * 8, 16)) = r.v;
    }
    for (int it = tid; it < 768 * 48; it += np) {         // Wih: 384x768
        int c3 = it % 768, kb = it / 768;
        union { unsigned short u[8]; uint4 v; } r;
        #pragma unroll
        for (int j = 0; j < 8; ++j) r.u[j] = f2bf(wih[(kb * 8 + j) * 768 + c3]);
        *(uint4*)(wgp + (c3 >> 8) * GATE_STRIDE + packIdx(c3 & 255, kb * 8, 20)) = r.v;
    }
    for (int it = tid; it < 768 * 32; it += np) {         // Whh: 256x768 (k offset 384)
        int c3 = it % 768, kb = it / 768;
        union { unsigned short u[8]; uint4 v; } r;
        #pragma unroll
        for (int j = 0; j < 8; ++j) r.u[j] = f2bf(whh[(kb * 8 + j) * 768 + c3]);
        *(uint4*)(wgp + (c3 >> 8) * GATE_STRIDE + packIdx(c3 & 255, 384 + kb * 8, 20)) = r.v;
    }
    for (int it = tid; it < 16 * 32; it += np) {          // Wo: 256x16
        int n = it & 15, kb = it >> 4;
        union { unsigned short u[8]; uint4 v; } r;
        #pragma unroll
        for (int j = 0; j < 8; ++j) r.u[j] = f2bf(wo[(kb * 8 + j) * 16 + n]);
        *(uint4*)(wop + packIdx(n, kb * 8, 8)) = r.v;
    }
}

// tiny separate scan (1 block x 1024 thr, ~4us): kernel boundary provides
// histogram visibility without any in-kernel device fence.
__global__ __launch_bounds__(1024) void scan_kernel(const int* __restrict__ deg,
                                                    int* __restrict__ off, int* __restrict__ cur) {
    __shared__ int part[1024];
    const int t = threadIdx.x;
    const int base = t * 20;
    int s = 0;
    #pragma unroll
    for (int i = 0; i < 20; ++i) { int idx = base + i; if (idx < N_NODES) s += deg[idx]; }
    part[t] = s;
    __syncthreads();
    int acc = s;
    for (int d = 1; d < 1024; d <<= 1) {
        int v = (t >= d) ? part[t - d] : 0;
        __syncthreads();
        acc += v; part[t] = acc;
        __syncthreads();
    }
    int run = acc - s;
    for (int i = 0; i < 20; ++i) {
        int idx = base + i;
        if (idx < N_NODES) { off[idx] = run; cur[idx] = run; run += deg[idx]; }
    }
}

// fused encoder + edge scatter (independent work, one dispatch):
// blocks 0..625: enc0 -> enc1 -> msg (R6 body, 32-row slab).
// blocks 626..3125: edge scatter -- its latency-bound atomics hide under
// the enc blocks' MFMA work instead of serializing (kept from R9: the
// fusion accounted for ~50us of R9's improvement).
__global__ __launch_bounds__(256) void enc_scatter_kernel(
    const unsigned short* __restrict__ featp, const unsigned short* __restrict__ hbp,
    const unsigned short* __restrict__ w0p, const float* __restrict__ b0,
    const unsigned short* __restrict__ w1p, const float* __restrict__ b1,
    const unsigned short* __restrict__ wmp, const float* __restrict__ mb,
    unsigned short* __restrict__ Xp, unsigned short* __restrict__ Mn,
    const int* __restrict__ src, const int* __restrict__ dst,
    int* __restrict__ cur, int* __restrict__ bucket)
{
    __shared__ __align__(16) unsigned short x0l[2][8][512];  // 16 KB
    __shared__ __align__(16) unsigned short x1l[2][8][512];  // 16 KB

    if (blockIdx.x >= 626) {
        // ---- scatter part ----
        int i = (blockIdx.x - 626) * 256 + threadIdx.x;
        if (i < N_EDGES) {
            int d = dst[i];
            int pos = atomicAdd(&cur[d], 1);
            if (pos < N_EDGES) bucket[pos] = src[i];   // replay-safe bound check
        }
        return;
    }

    // ---- enc part (R6 body, unchanged) ----
    const int wave = threadIdx.x >> 6;
    const int lane = threadIdx.x & 63, lr = lane & 15, lq = lane >> 4;
    const int m32 = blockIdx.x;          // 0..625
    int tG[2]; bool val[2];
    #pragma unroll
    for (int mf = 0; mf < 2; ++mf) { int tl = m32 * 2 + mf; val[mf] = tl < 1250; tG[mf] = val[mf] ? tl : 1249; }

    // ---- Stage A: X0 = relu(feat @ W0 + b0) -> LDS ----
    for (int i = 0; i < 4; ++i) {
        const int t = wave * 4 + i;
        f32x4 acc[2] = {{0,0,0,0},{0,0,0,0}};
        for (int c = 0; c < 2; ++c) {
            bf16x8 b = ld8(w0p + (t * 2 + c) * 512 + lane * 8);
            #pragma unroll
            for (int mf = 0; mf < 2; ++mf) {
                bf16x8 a = ld8(featp + (tG[mf] * 2 + c) * 512 + lane * 8);
                acc[mf] = mfma16(a, b, acc[mf]);
            }
        }
        float bias = b0[t * 16 + lr];
        #pragma unroll
        for (int mf = 0; mf < 2; ++mf)
            #pragma unroll
            for (int r = 0; r < 4; ++r)
                (&x0l[mf][0][0])[packIdxLoc(lq * 4 + r, t, lr)] = f2bf(fmaxf(acc[mf][r] + bias, 0.f));
    }
    __syncthreads();
    // ---- Stage B: X = relu(X0 @ W1 + b1) -> LDS + packed global ----
    for (int i = 0; i < 4; ++i) {
        const int t = wave * 4 + i;
        f32x4 acc[2] = {{0,0,0,0},{0,0,0,0}};
        for (int c = 0; c < 8; ++c) {
            bf16x8 b = ld8(w1p + (t * 8 + c) * 512 + lane * 8);
            #pragma unroll
            for (int mf = 0; mf < 2; ++mf) {
                bf16x8 a = ld8(&x0l[mf][c][lane * 8]);
                acc[mf] = mfma16(a, b, acc[mf]);
            }
        }
        float bias = b1[t * 16 + lr];
        #pragma unroll
        for (int mf = 0; mf < 2; ++mf)
            #pragma unroll
            for (int r = 0; r < 4; ++r) {
                unsigned short xb = f2bf(fmaxf(acc[mf][r] + bias, 0.f));
                (&x1l[mf][0][0])[packIdxLoc(lq * 4 + r, t, lr)] = xb;
                if (val[mf]) Xp[packIdxEp(tG[mf], lq * 4 + r, t, lr, 8)] = xb;
            }
    }
    __syncthreads();
    // ---- Stage C: Mnode = X @ Wx + h @ Wh + mb -> row-major global ----
    for (int i = 0; i < 2; ++i) {
        const int t = wave * 2 + i;          // 0..7
        const int col = t * 16 + lr;
        f32x4 acc[2] = {{0,0,0,0},{0,0,0,0}};
        for (int c = 0; c < 8; ++c) {        // X part, A from LDS
            bf16x8 b = ld8(wmp + (t * 16 + c) * 512 + lane * 8);
            #pragma unroll
            for (int mf = 0; mf < 2; ++mf) {
                bf16x8 a = ld8(&x1l[mf][c][lane * 8]);
                acc[mf] = mfma16(a, b, acc[mf]);
            }
        }
        for (int c = 0; c < 8; ++c) {        // h part
            bf16x8 b = ld8(wmp + (t * 16 + 8 + c) * 512 + lane * 8);
            #pragma unroll
            for (int mf = 0; mf < 2; ++mf) {
                bf16x8 a = ld8(hbp + (tG[mf] * 8 + c) * 512 + lane * 8);
                acc[mf] = mfma16(a, b, acc[mf]);
            }
        }
        float bias = mb[col];
        #pragma unroll
        for (int mf = 0; mf < 2; ++mf) if (val[mf])
            #pragma unroll
            for (int r = 0; r < 4; ++r) {
                int row = m32 * 32 + mf * 16 + lq * 4 + r;
                Mn[row * MSGD + col] = f2bf(acc[mf][r] + bias);
            }
    }
}

// one wave per node: gather Mn rows, mean, write packed C row.
// 2 rows per gather instruction: lanes 0-31 even edges, 32-63 odd edges,
// uint2/lane => 512 B/instr. Cross-half combine via shfl_xor(32).
__global__ __launch_bounds__(256) void aggregate_kernel(
    const int* __restrict__ off, const int* __restrict__ deg,
    const int* __restrict__ bucket, const unsigned short* __restrict__ Mn,
    unsigned short* __restrict__ Cp)
{
    const int wave = threadIdx.x >> 6;
    const int lane = threadIdx.x & 63;
    const int half = lane >> 5;          // 0: even edges, 1: odd edges
    const int l32  = lane & 31;          // cols 4*l32 .. 4*l32+3
    const int node = blockIdx.x * 4 + wave;
    if (node >= N_NODES) return;
    const int o = off[node], dg = deg[node];
    float s0 = 0.f, s1 = 0.f, s2 = 0.f, s3 = 0.f;
    const uint2* mn2 = (const uint2*)Mn;   // Mn row = 32 uint2
    int j = 0;
    for (; j + 8 <= dg; j += 8) {
        int ix[8];
        #pragma unroll
        for (int u = 0; u < 8; ++u) ix[u] = bucket[o + j + u];
        uint2 pk[4];
        #pragma unroll
        for (int p = 0; p < 4; ++p) pk[p] = mn2[ix[p * 2 + half] * 32 + l32];
        #pragma unroll
        for (int p = 0; p < 4; ++p) {
            s0 += bf2f((unsigned short)(pk[p].x & 0xffffu));
            s1 += bf2f((unsigned short)(pk[p].x >> 16));
            s2 += bf2f((unsigned short)(pk[p].y & 0xffffu));
            s3 += bf2f((unsigned short)(pk[p].y >> 16));
        }
    }
    for (; j + 2 <= dg; j += 2) {
        int i0 = bucket[o + j + half];
        uint2 pk = mn2[i0 * 32 + l32];
        s0 += bf2f((unsigned short)(pk.x & 0xffffu));
        s1 += bf2f((unsigned short)(pk.x >> 16));
        s2 += bf2f((unsigned short)(pk.y & 0xffffu));
        s3 += bf2f((unsigned short)(pk.y >> 16));
    }
    if (j < dg) {                         // odd remainder: only half 0 counts it
        int i0 = bucket[o + j];
        uint2 pk = mn2[i0 * 32 + l32];
        if (half == 0) {
            s0 += bf2f((unsigned short)(pk.x & 0xffffu));
            s1 += bf2f((unsigned short)(pk.x >> 16));
            s2 += bf2f((unsigned short)(pk.y & 0xffffu));
            s3 += bf2f((unsigned short)(pk.y >> 16));
        }
    }
    s0 += __shfl_xor(s0, 32);
    s1 += __shfl_xor(s1, 32);
    s2 += __shfl_xor(s2, 32);
    s3 += __shfl_xor(s3, 32);
    if (half == 0) {
        float invc = 1.0f / fmaxf((float)dg, 1.0f);
        uint2 outpk;
        outpk.x = ((unsigned int)f2bf(s1 * invc) << 16) | (unsigned int)f2bf(s0 * invc);
        outpk.y = ((unsigned int)f2bf(s3 * invc) << 16) | (unsigned int)f2bf(s2 * invc);
        *(uint2*)(Cp + packIdx(node, 4 * l32, 4)) = outpk;
    }
}

// ---------------- gru: XCD-partitioned persistent blocks + asm pipeline ----------------
// (unchanged from R5/R6 -- validated: gru < 41 us)
__global__ __launch_bounds__(512, 4) void gru_kernel(
    const unsigned short* __restrict__ Xp, const unsigned short* __restrict__ Cp,
    const unsigned short* __restrict__ hbp, const float* __restrict__ h,
    const unsigned short* __restrict__ wgp,
    const float* __restrict__ bih, const float* __restrict__ bhh,
    unsigned short* __restrict__ Hnp, float* __restrict__ out)
{
#define GL4(dst, ptr) asm volatile("global_load_dwordx4 %0, %1, off" : "=v"(dst) : "v"(ptr))
#define GLDW(dst, ptr, IMM) asm volatile("global_load_dword %0, %1, off offset:" #IMM : "=v"(dst) : "v"(ptr))
#define WAITV(N) do { asm volatile("s_waitcnt vmcnt(" #N ")" ::: "memory"); \
                      __builtin_amdgcn_sched_barrier(0); } while (0)
#define ISSUE2(cn) do { \
    const unsigned short *p0_, *p1_; \
    if ((cn) < 8)       { p0_ = bX + (cn) * 512;        p1_ = bX + 4096 + (cn) * 512; } \
    else if ((cn) < 12) { p0_ = bC + ((cn) - 8) * 512;  p1_ = bC + 2048 + ((cn) - 8) * 512; } \
    else                { p0_ = bH + ((cn) - 12) * 512; p1_ = bH + 4096 + ((cn) - 12) * 512; } \
    GL4(ring[(cn) & 3][0], p0_); GL4(ring[(cn) & 3][1], p1_); } while (0)
#define ISSUE1(cn) do { \
    const unsigned short *p_; \
    if ((cn) < 8)       p_ = bX + (cn) * 512; \
    else if ((cn) < 12) p_ = bC + ((cn) - 8) * 512; \
    else                p_ = bH + ((cn) - 12) * 512; \
    GL4(ring[(cn) & 3][0], p_); } while (0)
#define STEP(c, W) do { \
    bf16x8 br_ = ld8(&wlds[0][(c) * 512 + l8]); \
    bf16x8 bz_ = ld8(&wlds[1][(c) * 512 + l8]); \
    bf16x8 bn_ = ld8(&wlds[2][(c) * 512 + l8]); \
    WAITV(W); \
    bf16x8 a0_, a1_; \
    __builtin_memcpy(&a0_, &ring[(c) & 3][0], 16); \
    __builtin_memcpy(&a1_, &ring[(c) & 3][1], 16); \
    ar[0] = mfma16(a0_, br_, ar[0]);  ar[1] = mfma16(a1_, br_, ar[1]); \
    az[0] = mfma16(a0_, bz_, az[0]);  az[1] = mfma16(a1_, bz_, az[1]); \
    if ((c) < 12) { ani[0] = mfma16(a0_, bn_, ani[0]); ani[1] = mfma16(a1_, bn_, ani[1]); } \
    else          { anh[0] = mfma16(a0_, bn_, anh[0]); anh[1] = mfma16(a1_, bn_, anh[1]); } \
    if ((c) + 4 < 20) ISSUE2((c) + 4); \
    if ((c) == 15) { \
        GLDW(hov[0][0], hb0, 0); GLDW(hov[0][1], hb0, 1024); \
        GLDW(hov[0][2], hb0, 2048); GLDW(hov[0][3], hb0, 3072); \
        GLDW(hov[1][0], hb1, 0); GLDW(hov[1][1], hb1, 1024); \
        GLDW(hov[1][2], hb1, 2048); GLDW(hov[1][3], hb1, 3072); \
    } } while (0)
#define HSTEP(c, W) do { \
    bf16x8 br_ = ld8(&wlds[0][(c) * 512 + l8]); \
    bf16x8 bz_ = ld8(&wlds[1][(c) * 512 + l8]); \
    bf16x8 bn_ = ld8(&wlds[2][(c) * 512 + l8]); \
    WAITV(W); \
    bf16x8 a0_; \
    __builtin_memcpy(&a0_, &ring[(c) & 3][0], 16); \
    ar[0] = mfma16(a0_, br_, ar[0]); \
    az[0] = mfma16(a0_, bz_, az[0]); \
    if ((c) < 12) ani[0] = mfma16(a0_, bn_, ani[0]); \
    else          anh[0] = mfma16(a0_, bn_, anh[0]); \
    if ((c) + 4 < 20) ISSUE1((c) + 4); \
    if ((c) == 15) { \
        GLDW(hov[0][0], hb0, 0); GLDW(hov[0][1], hb0, 1024); \
        GLDW(hov[0][2], hb0, 2048); GLDW(hov[0][3], hb0, 3072); \
    } } while (0)
#define SETBASES32(m) do { \
    bX = Xp  + (m) * 8192 + l8; \
    bC = Cp  + (m) * 4096 + l8; \
    bH = hbp + (m) * 8192 + l8; \
    hb0 = h + ((m) * 32 + lq * 4) * HDIM + col; \
    hb1 = hb0 + 16 * HDIM; } while (0)
#define EPILOG32(m) do { \
    _Pragma("unroll") \
    for (int mf = 0; mf < 2; ++mf) \
        _Pragma("unroll") \
        for (int r = 0; r < 4; ++r) { \
            int row = (m) * 32 + mf * 16 + lq * 4 + r; \
            float rg = sigmoidf_(ar[mf][r] + bir); \
            float zg = sigmoidf_(az[mf][r] + biz); \
            float ng = tanhf_(ani[mf][r] + bin + rg * (anh[mf][r] + bhn)); \
            float hn = (1.0f - zg) * ng + zg * hov[mf][r]; \
            out[HN_OFF + row * HDIM + col] = hn; \
            Hnp[packIdxEp((m) * 2 + mf, lq * 4 + r, t, lr, 8)] = f2bf(hn); \
        } } while (0)
#define ACCINIT() do { \
    _Pragma("unroll") \
    for (int mf = 0; mf < 2; ++mf) { \
        ar[mf]  = (f32x4){0,0,0,0}; az[mf]  = (f32x4){0,0,0,0}; \
        ani[mf] = (f32x4){0,0,0,0}; anh[mf] = (f32x4){0,0,0,0}; } } while (0)

    __shared__ __align__(16) unsigned short wlds[3][10240];  // 60 KB

    const int b = blockIdx.x;            // 0..511
    const int x = b & 7;                 // XCD-partition label (%8 round-robin)
    const int i = b >> 3;                // 0..63
    const int t = i & 15;                // col tile (block-uniform)
    const int wi = i >> 4;               // 0..3
    const int tid = threadIdx.x;
    const int wv = tid >> 6;             // 0..7
    const int lane = tid & 63, lr = lane & 15, lq = lane >> 4;
    const int l8 = lane * 8;
    const int widx = wi * 8 + wv;        // 0..31 within (x,t)
    const int start = x * 78 + (x ? 1 : 0);
    const int cnt = 78 + (x == 0 ? 1 : 0);
    const int col = t * 16 + lr;

    const int m32a = start + widx;            // full tile 1
    const int m32b = start + 32 + widx;       // full tile 2
    const int halves = 2 * (cnt - 64);        // 28 or 30
    const bool has_tail = widx < halves;
    const int m32t = start + 64 + (widx >> 1);
    const int hm = widx & 1;                  // which 16-row half

    const unsigned short *bX, *bC, *bH;
    const float *hb0, *hb1;
    uint4 ring[4][2];
    f32x4 ar[2], az[2], ani[2], anh[2];
    float hov[2][4];

    // tile-A prologue BEFORE staging: staging loop + barrier (compiler emits
    // vmcnt(0) drain before s_barrier) hides + retires chunks 0..3.
    SETBASES32(m32a);
    ISSUE2(0); ISSUE2(1); ISSUE2(2); ISSUE2(3);

    // stage 3-gate weights for col-tile t: 61440 B = 3840 uint4 over 512 threads
    for (int s = tid; s < 3840; s += 512) {
        int g = s / 1280, rem = s - g * 1280;
        const uint4* sp = (const uint4*)(wgp + g * GATE_STRIDE + t * 10240) + rem;
        *((uint4*)(&wlds[g][0]) + rem) = *sp;
    }
    const float bir = bih[col] + bhh[col];
    const float biz = bih[256 + col] + bhh[256 + col];
    const float bin = bih[512 + col];
    const float bhn = bhh[512 + col];
    __syncthreads();

    // ---- tile A (m32a) ----
    ACCINIT();
    STEP(0, 22);  STEP(1, 22);  STEP(2, 22);  STEP(3, 22);
    STEP(4, 6);   STEP(5, 6);   STEP(6, 6);   STEP(7, 6);
    STEP(8, 6);   STEP(9, 6);   STEP(10, 6);  STEP(11, 6);
    STEP(12, 6);  STEP(13, 6);  STEP(14, 6);  STEP(15, 6);
    STEP(16, 14); STEP(17, 12); STEP(18, 10); STEP(19, 8);
    SETBASES32(m32b);
    ISSUE2(0); ISSUE2(1); ISSUE2(2); ISSUE2(3);
    WAITV(8);                      // retire hoA (8 prologue loads younger)
    EPILOG32(m32a);                // 16 stores

    // ---- tile B (m32b) ----
    ACCINIT();
    STEP(0, 22);  STEP(1, 22);  STEP(2, 22);  STEP(3, 22);
    STEP(4, 6);   STEP(5, 6);   STEP(6, 6);   STEP(7, 6);
    STEP(8, 6);   STEP(9, 6);   STEP(10, 6);  STEP(11, 6);
    STEP(12, 6);  STEP(13, 6);  STEP(14, 6);  STEP(15, 6);
    STEP(16, 14); STEP(17, 12); STEP(18, 10); STEP(19, 8);

    if (has_tail) {
        // half-tile bases: 16-row tile index = m32t*2 + hm
        bX = Xp  + (m32t * 2 + hm) * 4096 + l8;
        bC = Cp  + (m32t * 2 + hm) * 2048 + l8;
        bH = hbp + (m32t * 2 + hm) * 4096 + l8;
        hb0 = h + (m32t * 32 + hm * 16 + lq * 4) * HDIM + col;
        ISSUE1(0); ISSUE1(1); ISSUE1(2); ISSUE1(3);
        WAITV(4);                  // retire hoB (4 tail loads younger)
        EPILOG32(m32b);            // 16 stores
        // ---- half tile (m32t, half hm) ----
        ACCINIT();
        HSTEP(0, 19);  HSTEP(1, 19);  HSTEP(2, 19);  HSTEP(3, 19);
        HSTEP(4, 3);   HSTEP(5, 3);   HSTEP(6, 3);   HSTEP(7, 3);
        HSTEP(8, 3);   HSTEP(9, 3);   HSTEP(10, 3);  HSTEP(11, 3);
        HSTEP(12, 3);  HSTEP(13, 3);  HSTEP(14, 3);  HSTEP(15, 3);
        HSTEP(16, 7);  HSTEP(17, 6);  HSTEP(18, 5);  HSTEP(19, 4);
        WAITV(0);
        #pragma unroll
        for (int r = 0; r < 4; ++r) {
            int row = m32t * 32 + hm * 16 + lq * 4 + r;
            float rg = sigmoidf_(ar[0][r] + bir);
            float zg = sigmoidf_(az[0][r] + biz);
            float ng = tanhf_(ani[0][r] + bin + rg * (anh[0][r] + bhn));
            float hn = (1.0f - zg) * ng + zg * hov[0][r];
            out[HN_OFF + row * HDIM + col] = hn;
            Hnp[packIdxEp(m32t * 2 + hm, lq * 4 + r, t, lr, 8)] = f2bf(hn);
        }
    } else {
        WAITV(0);
        EPILOG32(m32b);
    }
#undef GL4
#undef GLDW
#undef WAITV
#undef ISSUE2
#undef ISSUE1
#undef STEP
#undef HSTEP
#undef SETBASES32
#undef EPILOG32
#undef ACCINIT
}

// q = h_new @ out_W + out_b. one wave per 16-row tile.
__global__ __launch_bounds__(256) void q_kernel(
    const unsigned short* __restrict__ Hnp, const unsigned short* __restrict__ wop,
    const float* __restrict__ ob, float* __restrict__ out)
{
    int w = blockIdx.x * 4 + (threadIdx.x >> 6);
    if (w >= 1250) w = 1249;
    const int lane = threadIdx.x & 63, lr = lane & 15, lq = lane >> 4;
    f32x4 acc = {0.f, 0.f, 0.f, 0.f};
    for (int c = 0; c < 8; ++c) {
        bf16x8 a = ld8(Hnp + (w * 8 + c) * 512 + lane * 8);
        bf16x8 b = ld8(wop + c * 512 + lane * 8);
        acc = mfma16(a, b, acc);
    }
    float bias = ob[lr];
    #pragma unroll
    for (int r = 0; r < 4; ++r)
        out[Q_OFF + (w * 16 + lq * 4 + r) * ADIM + lr] = acc[r] + bias;
}

extern "C" void kernel_launch(void* const* d_in, const int* in_sizes, int n_in,
                              void* d_out, int out_size, void* d_ws, size_t ws_size,
                              hipStream_t stream) {
    const float* feat = (const float*)d_in[0];
    const float* h    = (const float*)d_in[1];
    const int* src    = (const int*)d_in[2];
    const int* dst    = (const int*)d_in[3];
    const float* w0   = (const float*)d_in[4];
    const float* b0   = (const float*)d_in[5];
    const float* w1   = (const float*)d_in[6];
    const float* b1   = (const float*)d_in[7];
    const float* wm   = (const float*)d_in[8];
    const float* mb   = (const float*)d_in[9];
    const float* wih  = (const float*)d_in[10];
    const float* whh  = (const float*)d_in[11];
    const float* bih  = (const float*)d_in[12];
    const float* bhh  = (const float*)d_in[13];
    const float* wo   = (const float*)d_in[14];
    const float* ob   = (const float*)d_in[15];

    char* ws = (char*)d_ws;
    unsigned short* w0p   = (unsigned short*)(ws + WS_W0P);
    unsigned short* w1p   = (unsigned short*)(ws + WS_W1P);
    unsigned short* wmp   = (unsigned short*)(ws + WS_WMP);
    unsigned short* wgp   = (unsigned short*)(ws + WS_WGP);
    unsigned short* wop   = (unsigned short*)(ws + WS_WOP);
    unsigned short* featp = (unsigned short*)(ws + WS_FEATP);
    unsigned short* hbp   = (unsigned short*)(ws + WS_HBP);
    unsigned short* Xp    = (unsigned short*)(ws + WS_XP);
    unsigned short* Mn    = (unsigned short*)(ws + WS_MN);
    unsigned short* Cp    = (unsigned short*)(ws + WS_CP);
    unsigned short* Hnp   = (unsigned short*)(ws + WS_HNP);
    int* deg              = (int*)(ws + WS_DEG);
    int* off              = (int*)(ws + WS_OFF);
    int* cur              = (int*)(ws + WS_CUR);
    int* bucket           = (int*)(ws + WS_BUCKET);
    float* out            = (float*)d_out;

    hipMemsetAsync(deg, 0, 80000, stream);
    hipLaunchKernelGGL(setup_kernel, dim3(2048), dim3(256), 0, stream,
                       feat, h, w0, w1, wm, wih, whh, wo, dst,
                       featp, hbp, w0p, w1p, wmp, wgp, wop, deg);
    hipLaunchKernelGGL(scan_kernel, dim3(1), dim3(1024), 0, stream, deg, off, cur);
    hipLaunchKernelGGL(enc_scatter_kernel, dim3(626 + (N_EDGES + 255) / 256), dim3(256), 0, stream,
                       featp, hbp, w0p, b0, w1p, b1, wmp, mb, Xp, Mn,
                       src, dst, cur, bucket);
    hipLaunchKernelGGL(aggregate_kernel, dim3((N_NODES + 3) / 4), dim3(256), 0, stream,
                       off, deg, bucket, Mn, Cp);
    hipLaunchKernelGGL(gru_kernel, dim3(512), dim3(512), 0, stream,
                       Xp, Cp, hbp, h, wgp, bih, bhh, Hnp, out);
    hipLaunchKernelGGL(q_kernel, dim3(313), dim3(256), 0, stream, Hnp, wop, ob, out);
}